// Round 9
// baseline (609.327 us; speedup 1.0000x reference)
//
#include <hip/hip_runtime.h>

// ImplicitFunction MLP via fp16 MFMA (v_mfma_f32_32x32x16_f16), round 13.
// Round-13: persistent blocks — stage the 53KB weight image ONCE per block,
// then grid-stride over 4 point-tiles. Evidence: perf tracks occupancy/
// residency, not intra-wave schedule (57.3us@30% > 60.8@21% > 66@20%); the
// composed busy-cycle model (~12us) is 5x below measured 60us -> per-block
// serial overhead (staging + ramp + tail) repeated 8x/CU dominates the gap.
//  - grid = 512 blocks (2/CU, all co-resident; 2048 tiles / 512 = exactly 4
//    tiles per block -> uniform work, no dispatch rounds, no ragged tail).
//  - One staging + one __syncthreads per block; tile loop has NO barriers
//    (LDS read-only after staging) so waves free-run and de-phase.
//  - Body is byte-identical to the round-5 best (57.3us): single stream,
//    2 n-tiles/wave (64 pts), builtin MFMA, bias in C, setprio, fp32
//    epilogue, __launch_bounds__(512,4).
//  - #pragma unroll 1 on the tile loop (4 iterations; unrolling would spill).
//
// Layouts (gfx950, 32x32x16):
//   A/B frag: lane (i=lane&31, h=lane>>5) holds k = 8h+j, j=0..7
//   C/D:      col n = lane&31, row m = (r&3) + 8*(r>>2) + 4h, r=0..15
//   k-slot:   feat(s,h,j) = 16s + 8*(j>>2) + 4h + (j&3)

typedef _Float16 half8 __attribute__((ext_vector_type(8)));
typedef _Float16 half2v __attribute__((ext_vector_type(2)));
typedef float floatx16 __attribute__((ext_vector_type(16)));
typedef int int4v __attribute__((ext_vector_type(4)));

#define N_HID 6
// ws / LDS byte offsets (single contiguous image, staged wholesale)
#define OFF_A 0        // hidden W frags [l:6][t:2][s:4][lane:64][j:8] fp16 = 49152
#define OFF_B 49152    // layer0 A frags [t:2][lane:64][j:8] fp16          = 2048
#define OFF_C 51200    // bias/64 fp32, C-layout [l:7][h:2][t:2][r:16]     = 1792
#define OFF_D 52992    // wo*so*64 fp32, C-layout [h:2][t:2][r:16]         = 256
#define IMG_BYTES 53248
#define SETUP_TOTAL (24576 + 1024 + 448 + 64)

__global__ __launch_bounds__(256) void setup_weights(
    const float* __restrict__ w0, const float* __restrict__ s0, const float* __restrict__ b0,
    const float* __restrict__ wh, const float* __restrict__ sh, const float* __restrict__ bh,
    const float* __restrict__ wo, const float* __restrict__ so,
    unsigned char* __restrict__ ws)
{
    int i = blockIdx.x * 256 + threadIdx.x;
    if (i < 24576) {
        // hidden W frags with K-permutation baked in:
        // A[m][kslot(s,h,j)] = wh[l][feat][m] * sh[l][m], feat = 16s+8*(j>>2)+4h+(j&3)
        int j = i & 7, lane = (i >> 3) & 63, s = (i >> 9) & 3, t = (i >> 11) & 1, l = i >> 12;
        int m = 32 * t + (lane & 31);
        int h = lane >> 5;
        int feat = 16 * s + 8 * (j >> 2) + 4 * h + (j & 3);
        ((_Float16*)(ws + OFF_A))[i] = (_Float16)(wh[(l * 64 + feat) * 64 + m] * sh[l * 64 + m]);
    } else if (i < 24576 + 1024) {
        // layer-0 A frags (standard k order; B built from raw points)
        int i2 = i - 24576;
        int j = i2 & 7, lane = (i2 >> 3) & 63, t = i2 >> 9;
        int m = 32 * t + (lane & 31);
        int k = 8 * (lane >> 5) + j;
        float v = (k < 3) ? w0[k * 64 + m] * s0[m] * 0.015625f : 0.f;
        ((_Float16*)(ws + OFF_B))[i2] = (_Float16)v;
    } else if (i < 24576 + 1024 + 448) {
        // biases/64 in C layout
        int i2 = i - 24576 - 1024;
        int r = i2 & 15, t = (i2 >> 4) & 1, h = (i2 >> 5) & 1, l = i2 >> 6;
        int feat = 32 * t + (r & 3) + 8 * ((r >> 2) & 3) + 4 * h;
        float bv = (l == 0) ? b0[feat] : bh[(l - 1) * 64 + feat];
        ((float*)(ws + OFF_C))[i2] = bv * 0.015625f;
    } else if (i < SETUP_TOTAL) {
        // wo*so*64 in C layout
        int i2 = i - 24576 - 1024 - 448;
        int r = i2 & 15, t = (i2 >> 4) & 1, h = i2 >> 5;
        int feat = 32 * t + (r & 3) + 8 * ((r >> 2) & 3) + 4 * h;
        ((float*)(ws + OFF_D))[i2] = wo[feat] * so[0] * 64.f;
    }
}

static __device__ __forceinline__ int pkrtz(float a, float b) {
    auto hh = __builtin_amdgcn_cvt_pkrtz(a, b);  // v2f16, RTZ pack
    int r;
    __builtin_memcpy(&r, &hh, 4);
    return r;
}

// packed-fp16 leaky relu on a pair: max(u, 0.2*u) -> v_pk_mul_f16 + v_pk_max_f16
static __device__ __forceinline__ int lrelu2(int v) {
    half2v u;
    __builtin_memcpy(&u, &v, 4);
    half2v w = u * (_Float16)0.2f;
    half2v r = __builtin_elementwise_max(u, w);
    int o;
    __builtin_memcpy(&o, &r, 4);
    return o;
}

static __device__ __forceinline__ half8 as_h8(int4v v) {
    half8 r;
    __builtin_memcpy(&r, &v, 16);
    return r;
}

static __device__ __forceinline__ floatx16 mfma16(half8 a, half8 b, floatx16 c) {
    return __builtin_amdgcn_mfma_f32_32x32x16_f16(a, b, c, 0, 0, 0);
}

__global__ __launch_bounds__(512, 4) void mlp_mfma(
    const float* __restrict__ points,
    const unsigned char* __restrict__ ws,
    const float* __restrict__ bo,
    float* __restrict__ out, int n)
{
    __shared__ __align__(16) unsigned char lds[IMG_BYTES];

    // stage full weight image to LDS ONCE (53248 B = 3328 * 16; 512 threads)
    {
        const uint4* src = (const uint4*)ws;
        uint4* dst = (uint4*)lds;
#pragma unroll
        for (int i = 0; i < 6; ++i) {
            int idx = threadIdx.x + 512 * i;
            dst[idx] = src[idx];
        }
        if (threadIdx.x < 256) {
            int idx = 3072 + threadIdx.x;
            dst[idx] = src[idx];
        }
    }
    __syncthreads();   // the ONLY barrier; LDS is read-only afterwards

    const int lane = threadIdx.x & 63;
    const int wv = threadIdx.x >> 6;   // 0..7 (8 waves/block)
    const int p = lane & 31;
    const int h = lane >> 5;

    const half8* Wf = (const half8*)(lds + OFF_A);          // [l][t][s][lane]
    const half8* A0 = (const half8*)(lds + OFF_B);          // [t][lane]
    const floatx16* biasC = (const floatx16*)(lds + OFF_C); // [(l*2+h)*2+t]
    const floatx16* woC = (const floatx16*)(lds + OFF_D);   // [h*2+t]

    const int nt = (n + 511) >> 9;   // 512-point tiles
    const float bov = bo[0];

    // ---- persistent tile loop: each block handles nt/gridDim tiles ----
#pragma unroll 1
    for (int t = blockIdx.x; t < nt; t += gridDim.x) {
        const int base = t * 512 + wv * 64;
        const int pt0 = base + p, pt1 = base + 32 + p;
        const int pl0 = min(pt0, n - 1), pl1 = min(pt1, n - 1);

        floatx16 acc[2][2];   // [ntile][mtile]
        int4v frv[2][4];      // packed activations, [ntile][kstep]

        // ---- layer 0 ----
        {
            int4v z4 = {0, 0, 0, 0};
            int4v b0v = z4, b1v = z4;
            if (h == 0) {
                b0v[0] = pkrtz(points[3 * pl0 + 0], points[3 * pl0 + 1]);
                b0v[1] = pkrtz(points[3 * pl0 + 2], 0.f);
                b1v[0] = pkrtz(points[3 * pl1 + 0], points[3 * pl1 + 1]);
                b1v[1] = pkrtz(points[3 * pl1 + 2], 0.f);
            }
            floatx16 c0 = biasC[h * 2 + 0];   // l = 0
            floatx16 c1 = biasC[h * 2 + 1];
            half8 a0 = A0[lane], a1 = A0[64 + lane];
            __builtin_amdgcn_s_setprio(1);
            acc[0][0] = mfma16(a0, as_h8(b0v), c0);
            acc[0][1] = mfma16(a1, as_h8(b0v), c1);
            acc[1][0] = mfma16(a0, as_h8(b1v), c0);
            acc[1][1] = mfma16(a1, as_h8(b1v), c1);
            __builtin_amdgcn_s_setprio(0);
        }

        // pack + lrelu -> frv (also the next layer's B-frags, exchange-free)
        auto packfr = [&]() {
#pragma unroll
            for (int ntile = 0; ntile < 2; ++ntile)
#pragma unroll
                for (int tt = 0; tt < 2; ++tt)
#pragma unroll
                    for (int rp = 0; rp < 8; ++rp) {
                        int v = pkrtz(acc[ntile][tt][2 * rp], acc[ntile][tt][2 * rp + 1]);
                        int idx = 8 * tt + rp;
                        frv[ntile][idx >> 2][idx & 3] = lrelu2(v);
                    }
        };
        packfr();

        // ---- 6 hidden layers ----
        for (int l = 0; l < N_HID; ++l) {
            const floatx16 c0 = biasC[((l + 1) * 2 + h) * 2 + 0];
            const floatx16 c1 = biasC[((l + 1) * 2 + h) * 2 + 1];
            const half8* wl = Wf + l * 512 + lane;  // + t*256 + s*64
            __builtin_amdgcn_s_setprio(1);
            acc[0][0] = mfma16(wl[0],   as_h8(frv[0][0]), c0);
            acc[0][1] = mfma16(wl[256], as_h8(frv[0][0]), c1);
            acc[1][0] = mfma16(wl[0],   as_h8(frv[1][0]), c0);
            acc[1][1] = mfma16(wl[256], as_h8(frv[1][0]), c1);
#pragma unroll
            for (int s = 1; s < 4; ++s) {
                acc[0][0] = mfma16(wl[s * 64],       as_h8(frv[0][s]), acc[0][0]);
                acc[0][1] = mfma16(wl[256 + s * 64], as_h8(frv[0][s]), acc[0][1]);
                acc[1][0] = mfma16(wl[s * 64],       as_h8(frv[1][s]), acc[1][0]);
                acc[1][1] = mfma16(wl[256 + s * 64], as_h8(frv[1][s]), acc[1][1]);
            }
            __builtin_amdgcn_s_setprio(0);
            if (l < N_HID - 1) packfr();
        }

        // ---- output layer: fp32 lrelu + dot with wo (C-layout), cross-half reduce ----
        {
            floatx16 wo0 = woC[h * 2 + 0];
            floatx16 wo1 = woC[h * 2 + 1];
            float part0 = 0.f, part1 = 0.f;
#pragma unroll
            for (int r = 0; r < 16; ++r) {
                float u;
                u = acc[0][0][r]; part0 = fmaf(fmaxf(u, 0.2f * u), wo0[r], part0);
                u = acc[0][1][r]; part0 = fmaf(fmaxf(u, 0.2f * u), wo1[r], part0);
                u = acc[1][0][r]; part1 = fmaf(fmaxf(u, 0.2f * u), wo0[r], part1);
                u = acc[1][1][r]; part1 = fmaf(fmaxf(u, 0.2f * u), wo1[r], part1);
            }
            part0 += __shfl_xor(part0, 32);
            part1 += __shfl_xor(part1, 32);
            if (h == 0) {
                if (pt0 < n) out[pt0] = part0 + bov;
                if (pt1 < n) out[pt1] = part1 + bov;
            }
        }
    }
}

extern "C" void kernel_launch(void* const* d_in, const int* in_sizes, int n_in,
                              void* d_out, int out_size, void* d_ws, size_t ws_size,
                              hipStream_t stream) {
    const float* points = (const float*)d_in[0];
    const float* w0     = (const float*)d_in[1];
    const float* s0     = (const float*)d_in[2];
    const float* b0     = (const float*)d_in[3];
    const float* wh     = (const float*)d_in[4];
    const float* sh     = (const float*)d_in[5];
    const float* bh     = (const float*)d_in[6];
    const float* wo     = (const float*)d_in[7];
    const float* so     = (const float*)d_in[8];
    const float* bo     = (const float*)d_in[9];

    const int n = in_sizes[0] / 3;

    setup_weights<<<(SETUP_TOTAL + 255) / 256, 256, 0, stream>>>(
        w0, s0, b0, wh, sh, bh, wo, so, (unsigned char*)d_ws);

    // persistent: 512 blocks (2/CU co-resident), each handles exactly
    // nt/512 = 4 tiles of 512 points (n = 1M). No dispatch rounds, no tail.
    const int nt = (n + 511) / 512;
    const int grid = nt < 512 ? nt : 512;
    mlp_mfma<<<grid, 512, 0, stream>>>(
        points, (const unsigned char*)d_ws, bo, (float*)d_out, n);
}

// Round 10
// 129.284 us; speedup vs baseline: 4.7131x; 4.7131x over previous
//
#include <hip/hip_runtime.h>

// ImplicitFunction MLP via fp16 MFMA (v_mfma_f32_32x32x16_f16), round 14.
// Round-14: bias moved from the MFMA C-operand into the K-dimension.
// Evidence: r5 (the 57.3us best) shows ~2000 VALU inst/wave vs ~830 in
// source; the gap is AGPR<->VGPR copy traffic, half of which exists only to
// place the per-layer bias into the C operand (LDS->VGPR load + 32
// v_accvgpr_write per layer), plus the bias LDS latency sits on the
// per-layer critical path. Direct v-form-asm attacks failed (r9 NaN, r10
// null). Instead, delete the REASON for the copies:
//  - Layer 0: w0 uses only k=0..2 of 16 slots; b0/64 goes at k=3, B-frag
//    feeds 1.0 there (pkrtz(z,1.0) instead of pkrtz(z,0)). Zero extra cost.
//  - Hidden layers: per mtile one bias-MFMA (A5[m][k=0]=bh[m]/64, B4=1.0 at
//    slot 0 for h==0 lanes) whose D seeds the feature-kstep chain as C.
//    +2 MFMAs/layer replaces 32 accvgpr_writes + 2 LDS bias loads/layer.
//  - All C operands come from ONE hoisted zero tuple z (16 writes/kernel).
//    Pressure stays ~r5: z(+16 AGPR) is paid for by c0/c1 removal (-32 arch).
//  - Epilogue in packed f32 (v_pk_mul/max/fma_f32 via float2): ~192->~100 VALU.
//
// Carried from r5: 8 waves x 64 pts (2 n-tiles/wave), builtin MFMA (compiler
// handles hazard nops), K-permuted weights, packed-fp16 lrelu, activations
// scaled 1/64, 512-thread blocks, __launch_bounds__(512,4), setprio.
//
// Layouts (gfx950, 32x32x16):
//   A/B frag: lane (i=lane&31, h=lane>>5) holds k = 8h+j, j=0..7
//   C/D:      col n = lane&31, row m = (r&3) + 8*(r>>2) + 4h, r=0..15
//   k-slot:   feat(s,h,j) = 16s + 8*(j>>2) + 4h + (j&3)

typedef _Float16 half8 __attribute__((ext_vector_type(8)));
typedef _Float16 half2v __attribute__((ext_vector_type(2)));
typedef float floatx16 __attribute__((ext_vector_type(16)));
typedef float float2v __attribute__((ext_vector_type(2)));
typedef int int4v __attribute__((ext_vector_type(4)));

#define N_HID 6
// ws / LDS byte offsets (single contiguous image, staged wholesale)
#define OFF_A  0       // hidden W frags [l:6][t:2][s:4][lane:64][j:8] fp16 = 49152
#define OFF_A5 49152   // hidden bias A-frags [l:6][t:2][lane:64][j:8] fp16 = 12288
#define OFF_B  61440   // layer0 A frags (w0*s0/64; k=3 holds b0/64) fp16   = 2048
#define OFF_D  63488   // wo*so*64 fp32, C-layout [h:2][t:2][r:16]          = 256
#define IMG_BYTES 63744
#define SETUP_TOTAL (24576 + 6144 + 1024 + 64)   // 31808

__global__ __launch_bounds__(256) void setup_weights(
    const float* __restrict__ w0, const float* __restrict__ s0, const float* __restrict__ b0,
    const float* __restrict__ wh, const float* __restrict__ sh, const float* __restrict__ bh,
    const float* __restrict__ wo, const float* __restrict__ so,
    unsigned char* __restrict__ ws)
{
    int i = blockIdx.x * 256 + threadIdx.x;
    if (i < 24576) {
        // hidden W frags with K-permutation baked in:
        // A[m][kslot(s,h,j)] = wh[l][feat][m] * sh[l][m], feat = 16s+8*(j>>2)+4h+(j&3)
        int j = i & 7, lane = (i >> 3) & 63, s = (i >> 9) & 3, t = (i >> 11) & 1, l = i >> 12;
        int m = 32 * t + (lane & 31);
        int h = lane >> 5;
        int feat = 16 * s + 8 * (j >> 2) + 4 * h + (j & 3);
        ((_Float16*)(ws + OFF_A))[i] = (_Float16)(wh[(l * 64 + feat) * 64 + m] * sh[l * 64 + m]);
    } else if (i < 24576 + 6144) {
        // hidden bias A-frags: A5[m][k=0] = bh[m]/64 (slot h==0,j==0), else 0
        int i2 = i - 24576;
        int j = i2 & 7, lane = (i2 >> 3) & 63, t = (i2 >> 9) & 1, l = i2 >> 10;
        int m = 32 * t + (lane & 31);
        int h = lane >> 5;
        float v = (h == 0 && j == 0) ? bh[l * 64 + m] * 0.015625f : 0.f;
        ((_Float16*)(ws + OFF_A5))[i2] = (_Float16)v;
    } else if (i < 24576 + 6144 + 1024) {
        // layer-0 A frags: k<3 = w0*s0/64; k==3 = b0/64 (B supplies 1.0 there)
        int i2 = i - (24576 + 6144);
        int j = i2 & 7, lane = (i2 >> 3) & 63, t = i2 >> 9;
        int m = 32 * t + (lane & 31);
        int k = 8 * (lane >> 5) + j;
        float v = (k < 3) ? w0[k * 64 + m] * s0[m] * 0.015625f
                : (k == 3 ? b0[m] * 0.015625f : 0.f);
        ((_Float16*)(ws + OFF_B))[i2] = (_Float16)v;
    } else if (i < SETUP_TOTAL) {
        // wo*so*64 in C layout
        int i2 = i - (24576 + 6144 + 1024);
        int r = i2 & 15, t = (i2 >> 4) & 1, hh = i2 >> 5;
        int feat = 32 * t + (r & 3) + 8 * ((r >> 2) & 3) + 4 * hh;
        ((float*)(ws + OFF_D))[i2] = wo[feat] * so[0] * 64.f;
    }
}

static __device__ __forceinline__ int pkrtz(float a, float b) {
    auto hh = __builtin_amdgcn_cvt_pkrtz(a, b);  // v2f16, RTZ pack
    int r;
    __builtin_memcpy(&r, &hh, 4);
    return r;
}

// packed-fp16 leaky relu on a pair: max(u, 0.2*u) -> v_pk_mul_f16 + v_pk_max_f16
static __device__ __forceinline__ int lrelu2(int v) {
    half2v u;
    __builtin_memcpy(&u, &v, 4);
    half2v w = u * (_Float16)0.2f;
    half2v r = __builtin_elementwise_max(u, w);
    int o;
    __builtin_memcpy(&o, &r, 4);
    return o;
}

static __device__ __forceinline__ half8 as_h8(int4v v) {
    half8 r;
    __builtin_memcpy(&r, &v, 16);
    return r;
}

static __device__ __forceinline__ floatx16 mfma16(half8 a, half8 b, floatx16 c) {
    return __builtin_amdgcn_mfma_f32_32x32x16_f16(a, b, c, 0, 0, 0);
}

__global__ __launch_bounds__(512, 4) void mlp_mfma(
    const float* __restrict__ points,
    const unsigned char* __restrict__ ws,
    const float* __restrict__ bo,
    float* __restrict__ out, int n)
{
    __shared__ __align__(16) unsigned char lds[IMG_BYTES];

    // stage full weight image to LDS (63744 B = 3984 * 16; 512 threads)
    {
        const uint4* src = (const uint4*)ws;
        uint4* dst = (uint4*)lds;
#pragma unroll
        for (int i = 0; i < 7; ++i) {
            int idx = threadIdx.x + 512 * i;
            dst[idx] = src[idx];
        }
        if (threadIdx.x < 400) {
            int idx = 3584 + threadIdx.x;
            dst[idx] = src[idx];
        }
    }
    __syncthreads();

    const int lane = threadIdx.x & 63;
    const int wv = threadIdx.x >> 6;   // 0..7 (8 waves/block)
    const int p = lane & 31;
    const int h = lane >> 5;
    const int base = (blockIdx.x * 8 + wv) * 64;
    const int pt0 = base + p, pt1 = base + 32 + p;
    const int pl0 = min(pt0, n - 1), pl1 = min(pt1, n - 1);

    const half8* Wf = (const half8*)(lds + OFF_A);          // [l][t][s][lane]
    const half8* W5 = (const half8*)(lds + OFF_A5);         // [l][t][lane]
    const half8* A0 = (const half8*)(lds + OFF_B);          // [t][lane]
    const floatx16* woC = (const floatx16*)(lds + OFF_D);   // [h*2+t]

    floatx16 acc[2][2];   // [ntile][mtile]
    int4v frv[2][4];      // packed activations, [ntile][kstep] = B-frag

    // zero C operand (hoisted: 16 AGPR writes once per kernel)
    floatx16 z;
#pragma unroll
    for (int r = 0; r < 16; ++r) z[r] = 0.f;

    // bias-step B frag: fp16 1.0 at k-slot 0 (h==0, j==0), else 0
    int4v b4 = {(h == 0) ? 0x3C00 : 0, 0, 0, 0};

    // ---- layer 0 (bias via k=3 slot; C = z) ----
    {
        int4v b0v = {0, 0, 0, 0}, b1v = {0, 0, 0, 0};
        if (h == 0) {
            b0v[0] = pkrtz(points[3 * pl0 + 0], points[3 * pl0 + 1]);
            b0v[1] = pkrtz(points[3 * pl0 + 2], 1.0f);
            b1v[0] = pkrtz(points[3 * pl1 + 0], points[3 * pl1 + 1]);
            b1v[1] = pkrtz(points[3 * pl1 + 2], 1.0f);
        }
        half8 a0 = A0[lane], a1 = A0[64 + lane];
        __builtin_amdgcn_s_setprio(1);
        acc[0][0] = mfma16(a0, as_h8(b0v), z);
        acc[0][1] = mfma16(a1, as_h8(b0v), z);
        acc[1][0] = mfma16(a0, as_h8(b1v), z);
        acc[1][1] = mfma16(a1, as_h8(b1v), z);
        __builtin_amdgcn_s_setprio(0);
    }

    // pack + lrelu -> frv (also the next layer's B-frags, exchange-free)
    auto packfr = [&]() {
#pragma unroll
        for (int nt = 0; nt < 2; ++nt)
#pragma unroll
            for (int t = 0; t < 2; ++t)
#pragma unroll
                for (int rp = 0; rp < 8; ++rp) {
                    int v = pkrtz(acc[nt][t][2 * rp], acc[nt][t][2 * rp + 1]);
                    int idx = 8 * t + rp;
                    frv[nt][idx >> 2][idx & 3] = lrelu2(v);
                }
    };
    packfr();

    // ---- 6 hidden layers: bias-MFMA seeds the chain (no C copies) ----
    for (int l = 0; l < N_HID; ++l) {
        const half8* wl = Wf + l * 512 + lane;   // + t*256 + s*64
        const half8 w5t0 = W5[l * 128 + lane];
        const half8 w5t1 = W5[l * 128 + 64 + lane];
        __builtin_amdgcn_s_setprio(1);
        floatx16 bias0 = mfma16(w5t0, as_h8(b4), z);   // D[m][*] = bh[m]/64
        floatx16 bias1 = mfma16(w5t1, as_h8(b4), z);
        acc[0][0] = mfma16(wl[0],   as_h8(frv[0][0]), bias0);
        acc[0][1] = mfma16(wl[256], as_h8(frv[0][0]), bias1);
        acc[1][0] = mfma16(wl[0],   as_h8(frv[1][0]), bias0);
        acc[1][1] = mfma16(wl[256], as_h8(frv[1][0]), bias1);
#pragma unroll
        for (int s = 1; s < 4; ++s) {
            acc[0][0] = mfma16(wl[s * 64],       as_h8(frv[0][s]), acc[0][0]);
            acc[0][1] = mfma16(wl[256 + s * 64], as_h8(frv[0][s]), acc[0][1]);
            acc[1][0] = mfma16(wl[s * 64],       as_h8(frv[1][s]), acc[1][0]);
            acc[1][1] = mfma16(wl[256 + s * 64], as_h8(frv[1][s]), acc[1][1]);
        }
        __builtin_amdgcn_s_setprio(0);
        if (l < N_HID - 1) packfr();
    }

    // ---- output layer: packed-f32 lrelu + dot with wo, cross-half reduce ----
    {
        floatx16 wo0 = woC[h * 2 + 0];
        floatx16 wo1 = woC[h * 2 + 1];
        float2v pa0 = {0.f, 0.f}, pa1 = {0.f, 0.f};
#pragma unroll
        for (int rp = 0; rp < 8; ++rp) {
            float2v u, w;
            u = (float2v){acc[0][0][2 * rp], acc[0][0][2 * rp + 1]};
            w = (float2v){wo0[2 * rp], wo0[2 * rp + 1]};
            pa0 = __builtin_elementwise_fma(__builtin_elementwise_max(u, u * 0.2f), w, pa0);
            u = (float2v){acc[0][1][2 * rp], acc[0][1][2 * rp + 1]};
            w = (float2v){wo1[2 * rp], wo1[2 * rp + 1]};
            pa0 = __builtin_elementwise_fma(__builtin_elementwise_max(u, u * 0.2f), w, pa0);
            u = (float2v){acc[1][0][2 * rp], acc[1][0][2 * rp + 1]};
            w = (float2v){wo0[2 * rp], wo0[2 * rp + 1]};
            pa1 = __builtin_elementwise_fma(__builtin_elementwise_max(u, u * 0.2f), w, pa1);
            u = (float2v){acc[1][1][2 * rp], acc[1][1][2 * rp + 1]};
            w = (float2v){wo1[2 * rp], wo1[2 * rp + 1]};
            pa1 = __builtin_elementwise_fma(__builtin_elementwise_max(u, u * 0.2f), w, pa1);
        }
        float part0 = pa0[0] + pa0[1];
        float part1 = pa1[0] + pa1[1];
        part0 += __shfl_xor(part0, 32);
        part1 += __shfl_xor(part1, 32);
        const float bov = bo[0];
        if (h == 0) {
            if (pt0 < n) out[pt0] = part0 + bov;
            if (pt1 < n) out[pt1] = part1 + bov;
        }
    }
}

extern "C" void kernel_launch(void* const* d_in, const int* in_sizes, int n_in,
                              void* d_out, int out_size, void* d_ws, size_t ws_size,
                              hipStream_t stream) {
    const float* points = (const float*)d_in[0];
    const float* w0     = (const float*)d_in[1];
    const float* s0     = (const float*)d_in[2];
    const float* b0     = (const float*)d_in[3];
    const float* wh     = (const float*)d_in[4];
    const float* sh     = (const float*)d_in[5];
    const float* bh     = (const float*)d_in[6];
    const float* wo     = (const float*)d_in[7];
    const float* so     = (const float*)d_in[8];
    const float* bo     = (const float*)d_in[9];

    const int n = in_sizes[0] / 3;

    setup_weights<<<(SETUP_TOTAL + 255) / 256, 256, 0, stream>>>(
        w0, s0, b0, wh, sh, bh, wo, so, (unsigned char*)d_ws);

    const int grid = (n + 511) / 512;  // 512 points per block (8 waves x 64)
    mlp_mfma<<<grid, 512, 0, stream>>>(
        points, (const unsigned char*)d_ws, bo, (float*)d_out, n);
}